// Round 1
// baseline (175.994 us; speedup 1.0000x reference)
//
#include <hip/hip_runtime.h>
#include <hip/hip_bf16.h>

// LocalActivationUnit: score[b,t] = relu([q,k,q-k,q*k]·W0 + b0)·W1 + b1
// Folded form: Wb[e][h] = W0[128+e][h] - W0[256+e][h] + q[e]*W0[384+e][h]
//              bias[h]  = sum_e q[e]*(W0[e][h] + W0[256+e][h]) + b0[h]
//              h = relu(k·Wb + bias);  score = h·W1 + b1
// One block per batch b. Per-batch 200x128x64 bf16 MFMA GEMM, keys streamed
// from HBM exactly once (memory-bound target ~17us).
//
// R5 changes vs R4:
//  - fold vectorized along h: thread owns (4 h's, 8 e's), W0 read as float4
//    (32 load-instrs/thread instead of 128 scalar column loads)
//  - first m-tile keys prefetched into registers BEFORE the fold (independent)
//  - 2-deep software pipeline across m-tiles (prefetch mt+4 during compute of mt)
//  - __launch_bounds__(256,3): pipeline needs ~32 extra VGPRs; the old (256,4)
//    128-VGPR cap would spill (the R3 10x incident)

#define TB 200
#define EB 128
#define HB 64

typedef __attribute__((ext_vector_type(8))) short bf16x8;
typedef __attribute__((ext_vector_type(4))) float f32x4;

__global__ __launch_bounds__(256, 3)
void lau_kernel(const float* __restrict__ query,
                const float* __restrict__ keys,
                const float* __restrict__ W0,
                const float* __restrict__ b0,
                const float* __restrict__ W1,
                const float* __restrict__ b1,
                float* __restrict__ out)
{
    const int b    = blockIdx.x;
    const int tid  = threadIdx.x;
    const int lane = tid & 63;
    const int wave = tid >> 6;
    const int ln15 = lane & 15;
    const int quad = lane >> 4;

    __shared__ float q_s[EB];
    __shared__ float bias_s[HB];
    __shared__ float w1_s[HB];
    __shared__ float red2[HB][17];          // padded: 17 banks stride breaks conflicts
    // WbT[h][e] bf16, row stride 136 elems = 272 B. 272 % 128 == 16, so the
    // 16-byte ds_read_b128 fragments of lanes (ln15,quad) spread uniformly
    // across all 32 banks (structural minimum for b128).
    __shared__ __align__(16) __hip_bfloat16 wbt[HB][EB + 8];

    const float* kb = keys + (size_t)b * TB * EB;

    // q first (oldest in vmcnt queue -> fold barrier doesn't wait on keys)
    if (tid < EB) q_s[tid] = query[(size_t)b * EB + tid];

    // ---- prefetch first m-tile into registers (independent of fold) ----
    int mt = wave;
    float4 a[8];
    {
        const int mrow = mt * 16 + ln15;
        const int mc   = mrow < TB ? mrow : TB - 1;
        const float* arow = kb + (size_t)mc * EB + quad * 8;
        #pragma unroll
        for (int ks = 0; ks < 4; ++ks) {
            a[2*ks]   = *(const float4*)(arow + ks * 32);
            a[2*ks+1] = *(const float4*)(arow + ks * 32 + 4);
        }
    }
    __syncthreads();

    // ---- per-batch weight fold + bias partials (float4 along h) ----
    {
        const int hq = (tid & 15) * 4;      // h base: 0,4,...,60
        const int ck = tid >> 4;            // 0..15, each covers 8 e's
        float bp0 = 0.f, bp1 = 0.f, bp2 = 0.f, bp3 = 0.f;
        #pragma unroll
        for (int i = 0; i < 8; ++i) {
            const int e = ck * 8 + i;
            const float qe = q_s[e];
            const float4 wa = *(const float4*)&W0[(size_t)e            * HB + hq];
            const float4 wb = *(const float4*)&W0[(size_t)(EB + e)     * HB + hq];
            const float4 wc = *(const float4*)&W0[(size_t)(2 * EB + e) * HB + hq];
            const float4 wd = *(const float4*)&W0[(size_t)(3 * EB + e) * HB + hq];
            wbt[hq + 0][e] = __float2bfloat16(wb.x - wc.x + qe * wd.x);
            wbt[hq + 1][e] = __float2bfloat16(wb.y - wc.y + qe * wd.y);
            wbt[hq + 2][e] = __float2bfloat16(wb.z - wc.z + qe * wd.z);
            wbt[hq + 3][e] = __float2bfloat16(wb.w - wc.w + qe * wd.w);
            bp0 += qe * (wa.x + wc.x);
            bp1 += qe * (wa.y + wc.y);
            bp2 += qe * (wa.z + wc.z);
            bp3 += qe * (wa.w + wc.w);
        }
        red2[hq + 0][ck] = bp0;
        red2[hq + 1][ck] = bp1;
        red2[hq + 2][ck] = bp2;
        red2[hq + 3][ck] = bp3;
    }
    __syncthreads();
    if (tid < HB) {
        float s = b0[tid];
        #pragma unroll
        for (int c = 0; c < 16; ++c) s += red2[tid][c];
        bias_s[tid] = s;
        w1_s[tid]   = W1[tid];
    }
    __syncthreads();

    float w1q[4], biasq[4];
    #pragma unroll
    for (int nt = 0; nt < 4; ++nt) {
        w1q[nt]   = w1_s[nt * 16 + ln15];
        biasq[nt] = bias_s[nt * 16 + ln15];
    }

    // Per-lane LDS base for B-fragments: WbT[ln15][quad*8], nt adds 4352 B,
    // ks adds 64 B -> compiler folds into ds_read_b128 offsets.
    const __hip_bfloat16* wb_base = &wbt[ln15][quad * 8];
    const float b1v = b1[0];

    // 13 m-tiles of 16 rows cover T=200 (last tile half-masked).
    // 2-deep pipeline: issue loads for mt+4 (clamped) before computing mt.
    for (; mt < 13; mt += 4) {
        const int mtn   = (mt + 4 < 13) ? (mt + 4) : 12;   // clamp: L1-hot re-read
        const int mrowN = mtn * 16 + ln15;
        const int mcN   = mrowN < TB ? mrowN : TB - 1;
        const float* arowN = kb + (size_t)mcN * EB + quad * 8;
        float4 an[8];
        #pragma unroll
        for (int ks = 0; ks < 4; ++ks) {
            an[2*ks]   = *(const float4*)(arowN + ks * 32);
            an[2*ks+1] = *(const float4*)(arowN + ks * 32 + 4);
        }

        f32x4 acc[4] = {{0,0,0,0},{0,0,0,0},{0,0,0,0},{0,0,0,0}};
        #pragma unroll
        for (int ks = 0; ks < 4; ++ks) {
            union { bf16x8 v; __hip_bfloat162 h2[4]; } u;
            u.h2[0] = __float22bfloat162_rn(make_float2(a[2*ks].x,   a[2*ks].y));
            u.h2[1] = __float22bfloat162_rn(make_float2(a[2*ks].z,   a[2*ks].w));
            u.h2[2] = __float22bfloat162_rn(make_float2(a[2*ks+1].x, a[2*ks+1].y));
            u.h2[3] = __float22bfloat162_rn(make_float2(a[2*ks+1].z, a[2*ks+1].w));
            #pragma unroll
            for (int nt = 0; nt < 4; ++nt) {
                const bf16x8 bf = *(const bf16x8*)(wb_base + nt * 16 * (EB + 8) + ks * 32);
                acc[nt] = __builtin_amdgcn_mfma_f32_16x16x32_bf16(u.v, bf, acc[nt], 0, 0, 0);
            }
        }

        // ---- epilogue: relu + bias, dot with W1, reduce over n (16 lanes) ----
        // C layout: n = ln15, m(in-tile) = quad*4 + r
        float part[4];
        #pragma unroll
        for (int r = 0; r < 4; ++r) {
            float s = 0.f;
            #pragma unroll
            for (int nt = 0; nt < 4; ++nt) {
                float hv = acc[nt][r] + biasq[nt];
                hv = hv > 0.f ? hv : 0.f;
                s += hv * w1q[nt];
            }
            part[r] = s;
        }
        #pragma unroll
        for (int m = 1; m < 16; m <<= 1) {
            #pragma unroll
            for (int r = 0; r < 4; ++r)
                part[r] += __shfl_xor(part[r], m, 64);
        }
        if (ln15 == 0) {
            #pragma unroll
            for (int r = 0; r < 4; ++r) {
                const int mg = mt * 16 + quad * 4 + r;
                if (mg < TB) out[(size_t)b * TB + mg] = part[r] + b1v;
            }
        }

        // rotate pipeline registers
        #pragma unroll
        for (int i = 0; i < 8; ++i) a[i] = an[i];
    }
}

extern "C" void kernel_launch(void* const* d_in, const int* in_sizes, int n_in,
                              void* d_out, int out_size, void* d_ws, size_t ws_size,
                              hipStream_t stream) {
    const float* query = (const float*)d_in[0];
    const float* keys  = (const float*)d_in[1];
    const float* W0    = (const float*)d_in[2];
    const float* b0    = (const float*)d_in[3];
    const float* W1    = (const float*)d_in[4];
    const float* b1    = (const float*)d_in[5];
    float* out = (float*)d_out;

    lau_kernel<<<1024, 256, 0, stream>>>(query, keys, W0, b0, W1, b1, out);
}